// Round 4
// baseline (1619.196 us; speedup 1.0000x reference)
//
#include <hip/hip_runtime.h>
#include <math.h>

#define NROWS 16384      // 32*512
#define DDIM  512
#define NE    4096
#define SPLIT 16
#define CPS   (NE / SPLIT)   // 256 codes per split
#define TM    128
#define TN    128
#define KT    16
#define LDP   132            // padded LDS row stride (16B aligned, conflict-free)
#define NZ    (NROWS * DDIM) // 8388608

__device__ __forceinline__ float sqr_rn(float x) { return __fmul_rn(x, x); }

// ---------------- kernel 0a: numpy-exact pairwise partial sums of z*z ----------------
__global__ void k_znormB(const float* __restrict__ z, float* __restrict__ Bsum) {
    const int t = blockIdx.x * blockDim.x + threadIdx.x;   // 0 .. NROWS*4-1
    const int row = t >> 2, blk = t & 3;
    const float4* p = (const float4*)(z + (size_t)row * DDIM + blk * 128);
    float4 v0 = p[0], v1 = p[1];
    float r[8];
    r[0] = sqr_rn(v0.x); r[1] = sqr_rn(v0.y); r[2] = sqr_rn(v0.z); r[3] = sqr_rn(v0.w);
    r[4] = sqr_rn(v1.x); r[5] = sqr_rn(v1.y); r[6] = sqr_rn(v1.z); r[7] = sqr_rn(v1.w);
    #pragma unroll
    for (int i = 1; i < 16; ++i) {
        v0 = p[2 * i]; v1 = p[2 * i + 1];
        r[0] = __fadd_rn(r[0], sqr_rn(v0.x)); r[1] = __fadd_rn(r[1], sqr_rn(v0.y));
        r[2] = __fadd_rn(r[2], sqr_rn(v0.z)); r[3] = __fadd_rn(r[3], sqr_rn(v0.w));
        r[4] = __fadd_rn(r[4], sqr_rn(v1.x)); r[5] = __fadd_rn(r[5], sqr_rn(v1.y));
        r[6] = __fadd_rn(r[6], sqr_rn(v1.z)); r[7] = __fadd_rn(r[7], sqr_rn(v1.w));
    }
    Bsum[t] = __fadd_rn(__fadd_rn(__fadd_rn(r[0], r[1]), __fadd_rn(r[2], r[3])),
                        __fadd_rn(__fadd_rn(r[4], r[5]), __fadd_rn(r[6], r[7])));
}

// ---------------- kernel 0b: combine 4 block sums: (B0+B1)+(B2+B3) ----------------
__global__ void k_znfin(const float* __restrict__ Bsum, float* __restrict__ znorm) {
    const int row = blockIdx.x * blockDim.x + threadIdx.x;
    if (row >= NROWS) return;
    const float4 b = *(const float4*)(Bsum + (size_t)row * 4);
    znorm[row] = __fadd_rn(__fadd_rn(b.x, b.y), __fadd_rn(b.z, b.w));
}

// ---------------- kernel 1: codebook squared norms (sub-ulp of zz; order-free) ----------
__global__ void k_bnorm(const float* __restrict__ emb, float* __restrict__ bnorm) {
    const int lane = threadIdx.x & 63;
    const int wid  = (blockIdx.x * blockDim.x + threadIdx.x) >> 6;
    const int nw   = (gridDim.x * blockDim.x) >> 6;
    for (int c = wid; c < NE; c += nw) {
        const float4* p = (const float4*)(emb + (size_t)c * DDIM);
        float4 v0 = p[lane * 2];
        float4 v1 = p[lane * 2 + 1];
        float s = v0.x*v0.x + v0.y*v0.y + v0.z*v0.z + v0.w*v0.w
                + v1.x*v1.x + v1.y*v1.y + v1.z*v1.z + v1.w*v1.w;
        #pragma unroll
        for (int m = 32; m; m >>= 1) s += __shfl_xor(s, m);
        if (lane == 0) bnorm[c] = s;
    }
}

// ---------------- kernel 2: fused distance GEMM + per-split argmin ----------------
// grid (NROWS/TM, SPLIT), block 256 (tx 0..15, ty 0..15). 8x8 microtile.
// B-fragment = two contiguous 4-col b128 reads (conflict-free); LDS stride 132.
// d = fl(fl(zz+ee) - fl(2*dot)), dot = sequential ascending-k FMA chain (bit-exact vs np).
__global__ __launch_bounds__(256, 4) void k_dist(const float* __restrict__ z,
                                                 const float* __restrict__ emb,
                                                 const float* __restrict__ bnorm,
                                                 const float* __restrict__ znorm,
                                                 unsigned long long* __restrict__ minkey) {
    __shared__ float As[KT][LDP];
    __shared__ float Bs[KT][LDP];
    const int tid = threadIdx.x;
    const int tx = tid & 15, ty = tid >> 4;
    const int rbase = blockIdx.x * TM;
    const int split = blockIdx.y;
    const int rc0 = tid >> 2;               // 0..63
    const int kq  = (tid & 3) * 4;          // 0,4,8,12

    float zn[8];
    #pragma unroll
    for (int i = 0; i < 8; ++i) zn[i] = znorm[rbase + ty * 8 + i];

    unsigned long long best[8];
    #pragma unroll
    for (int i = 0; i < 8; ++i) best[i] = ~0ULL;

    for (int ct = 0; ct < CPS / TN; ++ct) {
        const int cb = split * CPS + ct * TN;
        float acc[8][8];
        #pragma unroll
        for (int i = 0; i < 8; ++i)
            #pragma unroll
            for (int j = 0; j < 8; ++j) acc[i][j] = 0.f;

        // prefetch k-tile 0
        float4 vaA = *(const float4*)(z   + (size_t)(rbase + rc0)      * DDIM + kq);
        float4 vaB = *(const float4*)(z   + (size_t)(rbase + rc0 + 64) * DDIM + kq);
        float4 vbA = *(const float4*)(emb + (size_t)(cb + rc0)         * DDIM + kq);
        float4 vbB = *(const float4*)(emb + (size_t)(cb + rc0 + 64)    * DDIM + kq);

        for (int kb = 0; kb < DDIM; kb += KT) {
            // transpose-stage into LDS (2-way banked = free)
            As[kq+0][rc0]    = vaA.x; As[kq+1][rc0]    = vaA.y; As[kq+2][rc0]    = vaA.z; As[kq+3][rc0]    = vaA.w;
            As[kq+0][rc0+64] = vaB.x; As[kq+1][rc0+64] = vaB.y; As[kq+2][rc0+64] = vaB.z; As[kq+3][rc0+64] = vaB.w;
            Bs[kq+0][rc0]    = vbA.x; Bs[kq+1][rc0]    = vbA.y; Bs[kq+2][rc0]    = vbA.z; Bs[kq+3][rc0]    = vbA.w;
            Bs[kq+0][rc0+64] = vbB.x; Bs[kq+1][rc0+64] = vbB.y; Bs[kq+2][rc0+64] = vbB.z; Bs[kq+3][rc0+64] = vbB.w;
            __syncthreads();
            if (kb + KT < DDIM) {   // prefetch next tile; latency hides under FMAs
                const int ko = kb + KT + kq;
                vaA = *(const float4*)(z   + (size_t)(rbase + rc0)      * DDIM + ko);
                vaB = *(const float4*)(z   + (size_t)(rbase + rc0 + 64) * DDIM + ko);
                vbA = *(const float4*)(emb + (size_t)(cb + rc0)         * DDIM + ko);
                vbB = *(const float4*)(emb + (size_t)(cb + rc0 + 64)    * DDIM + ko);
            }
            #pragma unroll
            for (int k = 0; k < KT; ++k) {      // strictly ascending k
                float4 a0 = *(const float4*)&As[k][ty * 8];
                float4 a1 = *(const float4*)&As[k][ty * 8 + 4];
                float4 b0 = *(const float4*)&Bs[k][tx * 4];        // cols 4tx..4tx+3
                float4 b1 = *(const float4*)&Bs[k][64 + tx * 4];   // cols 64+4tx..+3
                float av[8] = {a0.x,a0.y,a0.z,a0.w,a1.x,a1.y,a1.z,a1.w};
                float bv[8] = {b0.x,b0.y,b0.z,b0.w,b1.x,b1.y,b1.z,b1.w};
                #pragma unroll
                for (int i = 0; i < 8; ++i)
                    #pragma unroll
                    for (int j = 0; j < 8; ++j)
                        acc[i][j] = fmaf(av[i], bv[j], acc[i][j]);
            }
            __syncthreads();
        }
        // epilogue: d = fl(fl(zz+ee) - fl(2*dot)); pack (bits(d), col) into u64 min-key
        #pragma unroll
        for (int j = 0; j < 8; ++j) {
            const int col = cb + ((j < 4) ? (tx * 4 + j) : (64 + tx * 4 + (j - 4)));
            const float bn = bnorm[col];
            #pragma unroll
            for (int i = 0; i < 8; ++i) {
                const float s = __fsub_rn(__fadd_rn(zn[i], bn), __fmul_rn(2.f, acc[i][j]));
                const unsigned long long key =
                    ((unsigned long long)__float_as_uint(s) << 32) | (unsigned)col;
                if (key < best[i]) best[i] = key;
            }
        }
    }

    // min-key reduce across the 16 tx lanes (same ty group)
    #pragma unroll
    for (int i = 0; i < 8; ++i) {
        unsigned long long v = best[i];
        #pragma unroll
        for (int m = 1; m < 16; m <<= 1) {
            unsigned long long ov = __shfl_xor(v, m);
            if (ov < v) v = ov;
        }
        if (tx == 0) minkey[(size_t)(rbase + ty * 8 + i) * SPLIT + split] = v;
    }
}

// ---------------- kernel 3: final argmin over splits + gather + STE + partials ----------------
__global__ void k_gather(const float* __restrict__ z, const float* __restrict__ emb,
                         const unsigned long long* __restrict__ minkey,
                         float* __restrict__ out, unsigned* __restrict__ counts,
                         float* __restrict__ d2buf) {
    const int lane = threadIdx.x & 63;
    const int row = blockIdx.x * 4 + (threadIdx.x >> 6);
    unsigned long long v = ~0ULL;
    if (lane < SPLIT) v = minkey[(size_t)row * SPLIT + lane];
    #pragma unroll
    for (int m = 32; m; m >>= 1) {
        unsigned long long ov = __shfl_xor(v, m);
        if (ov < v) v = ov;
    }
    const int id = (int)(v & 0xffffffffu);

    const float* ep = emb + (size_t)id * DDIM;
    const float* zp = z + (size_t)row * DDIM;
    float* op = out + 1 + (size_t)row * DDIM;
    float d2 = 0.f;
    #pragma unroll
    for (int m = 0; m < 8; ++m) {                   // stride-1 coalesced
        const int k = m * 64 + lane;
        const float e = ep[k];
        const float zv = zp[k];
        const float t = e - zv;                     // two-step rounding matches reference STE
        op[k] = zv + t;
        d2 = fmaf(t, t, d2);
    }
    #pragma unroll
    for (int m = 32; m; m >>= 1) d2 += __shfl_xor(d2, m);
    if (lane == 0) {
        atomicAdd(&counts[id], 1u);
        d2buf[row] = d2;
        out[1 + (size_t)NZ + row] = (float)id;
    }
}

// ---------------- kernel 4: finalize loss + perplexity ----------------
__global__ void k_final(const float* __restrict__ d2buf, const unsigned* __restrict__ counts,
                        float* __restrict__ out) {
    __shared__ double sh[256];
    __shared__ float  shf[256];
    const int tid = threadIdx.x;
    double ent = 0.0;
    for (int i = tid; i < NE; i += 256) {
        const double p = (double)counts[i] / (double)NROWS;
        ent += p * log(p + 1e-10);
    }
    float sse = 0.f;
    for (int i = tid; i < NROWS; i += 256) sse += d2buf[i];
    sh[tid] = ent; shf[tid] = sse;
    __syncthreads();
    for (int s = 128; s; s >>= 1) {
        if (tid < s) { sh[tid] += sh[tid + s]; shf[tid] += shf[tid + s]; }
        __syncthreads();
    }
    if (tid == 0) {
        out[0] = 1.25f * (shf[0] / (float)NZ);
        out[1 + (size_t)NZ + NROWS] = (float)exp(-sh[0]);
    }
}

extern "C" void kernel_launch(void* const* d_in, const int* in_sizes, int n_in,
                              void* d_out, int out_size, void* d_ws, size_t ws_size,
                              hipStream_t stream) {
    const float* z   = (const float*)d_in[0];
    const float* emb = (const float*)d_in[1];
    float* out = (float*)d_out;
    char* ws = (char*)d_ws;

    size_t off = 0;
    unsigned long long* minkey = (unsigned long long*)(ws + off);
    off += (size_t)NROWS * SPLIT * 8;                                          // 2MB
    float*    bnorm  = (float*)(ws + off); off += (size_t)NE * 4;              // 16KB
    unsigned* counts = (unsigned*)(ws + off); off += (size_t)NE * 4;           // 16KB
    float*    d2buf  = (float*)(ws + off); off += (size_t)NROWS * 4;           // 64KB
    float*    Bsum   = (float*)(ws + off); off += (size_t)NROWS * 4 * 4;       // 256KB
    float*    znorm  = (float*)(ws + off); off += (size_t)NROWS * 4;           // 64KB

    hipMemsetAsync(counts, 0, NE * sizeof(unsigned), stream);
    k_znormB<<<(NROWS * 4) / 256, 256, 0, stream>>>(z, Bsum);
    k_znfin<<<NROWS / 256, 256, 0, stream>>>(Bsum, znorm);
    k_bnorm<<<64, 256, 0, stream>>>(emb, bnorm);
    k_dist<<<dim3(NROWS / TM, SPLIT), 256, 0, stream>>>(z, emb, bnorm, znorm, minkey);
    k_gather<<<NROWS / 4, 256, 0, stream>>>(z, emb, minkey, out, counts, d2buf);
    k_final<<<1, 256, 0, stream>>>(d2buf, counts, out);
}

// Round 5
// 1134.945 us; speedup vs baseline: 1.4267x; 1.4267x over previous
//
#include <hip/hip_runtime.h>
#include <math.h>

#define NROWS 16384      // 32*512
#define DDIM  512
#define NE    4096
#define SPLIT 8
#define CPS   (NE / SPLIT)   // 512 codes per split
#define TM    128
#define TN    128
#define KT    16
#define LDP   132            // padded LDS row stride (16B aligned, conflict-free)
#define NZ    (NROWS * DDIM) // 8388608

__device__ __forceinline__ float sqr_rn(float x) { return __fmul_rn(x, x); }

// ---------------- kernel 0a: numpy-exact pairwise partial sums of z*z ----------------
__global__ void k_znormB(const float* __restrict__ z, float* __restrict__ Bsum) {
    const int t = blockIdx.x * blockDim.x + threadIdx.x;   // 0 .. NROWS*4-1
    const int row = t >> 2, blk = t & 3;
    const float4* p = (const float4*)(z + (size_t)row * DDIM + blk * 128);
    float4 v0 = p[0], v1 = p[1];
    float r[8];
    r[0] = sqr_rn(v0.x); r[1] = sqr_rn(v0.y); r[2] = sqr_rn(v0.z); r[3] = sqr_rn(v0.w);
    r[4] = sqr_rn(v1.x); r[5] = sqr_rn(v1.y); r[6] = sqr_rn(v1.z); r[7] = sqr_rn(v1.w);
    #pragma unroll
    for (int i = 1; i < 16; ++i) {
        v0 = p[2 * i]; v1 = p[2 * i + 1];
        r[0] = __fadd_rn(r[0], sqr_rn(v0.x)); r[1] = __fadd_rn(r[1], sqr_rn(v0.y));
        r[2] = __fadd_rn(r[2], sqr_rn(v0.z)); r[3] = __fadd_rn(r[3], sqr_rn(v0.w));
        r[4] = __fadd_rn(r[4], sqr_rn(v1.x)); r[5] = __fadd_rn(r[5], sqr_rn(v1.y));
        r[6] = __fadd_rn(r[6], sqr_rn(v1.z)); r[7] = __fadd_rn(r[7], sqr_rn(v1.w));
    }
    Bsum[t] = __fadd_rn(__fadd_rn(__fadd_rn(r[0], r[1]), __fadd_rn(r[2], r[3])),
                        __fadd_rn(__fadd_rn(r[4], r[5]), __fadd_rn(r[6], r[7])));
}

// ---------------- kernel 0b: combine 4 block sums: (B0+B1)+(B2+B3) ----------------
__global__ void k_znfin(const float* __restrict__ Bsum, float* __restrict__ znorm) {
    const int row = blockIdx.x * blockDim.x + threadIdx.x;
    if (row >= NROWS) return;
    const float4 b = *(const float4*)(Bsum + (size_t)row * 4);
    znorm[row] = __fadd_rn(__fadd_rn(b.x, b.y), __fadd_rn(b.z, b.w));
}

// ---------------- kernel 1: codebook squared norms (sub-ulp of zz; order-free) ----------
__global__ void k_bnorm(const float* __restrict__ emb, float* __restrict__ bnorm) {
    const int lane = threadIdx.x & 63;
    const int wid  = (blockIdx.x * blockDim.x + threadIdx.x) >> 6;
    const int nw   = (gridDim.x * blockDim.x) >> 6;
    for (int c = wid; c < NE; c += nw) {
        const float4* p = (const float4*)(emb + (size_t)c * DDIM);
        float4 v0 = p[lane * 2];
        float4 v1 = p[lane * 2 + 1];
        float s = v0.x*v0.x + v0.y*v0.y + v0.z*v0.z + v0.w*v0.w
                + v1.x*v1.x + v1.y*v1.y + v1.z*v1.z + v1.w*v1.w;
        #pragma unroll
        for (int m = 32; m; m >>= 1) s += __shfl_xor(s, m);
        if (lane == 0) bnorm[c] = s;
    }
}

// ---------------- kernel 2: fused distance GEMM + per-split argmin ----------------
// grid (NROWS/TM, SPLIT), block 256 (tx 0..15, ty 0..15). 8x8 microtile.
// B-fragment = two contiguous 4-col b128 reads (conflict-free); LDS stride 132.
// d = fl(fl(zz+ee) - fl(2*dot)), dot = sequential ascending-k FMA chain (bit-exact vs np).
// NOTE: no min-waves clause — __launch_bounds__(256,4) capped VGPR at 64 and spilled
// (R4: WRITE_SIZE 4.6 GB of scratch). Kernel needs ~110 regs live.
__global__ __launch_bounds__(256) void k_dist(const float* __restrict__ z,
                                              const float* __restrict__ emb,
                                              const float* __restrict__ bnorm,
                                              const float* __restrict__ znorm,
                                              unsigned long long* __restrict__ minkey) {
    __shared__ float As[KT][LDP];
    __shared__ float Bs[KT][LDP];
    const int tid = threadIdx.x;
    const int tx = tid & 15, ty = tid >> 4;
    const int rbase = blockIdx.x * TM;
    const int split = blockIdx.y;
    const int rc0 = tid >> 2;               // 0..63
    const int kq  = (tid & 3) * 4;          // 0,4,8,12

    float zn[8];
    #pragma unroll
    for (int i = 0; i < 8; ++i) zn[i] = znorm[rbase + ty * 8 + i];

    unsigned long long best[8];
    #pragma unroll
    for (int i = 0; i < 8; ++i) best[i] = ~0ULL;

    for (int ct = 0; ct < CPS / TN; ++ct) {
        const int cb = split * CPS + ct * TN;
        float acc[8][8];
        #pragma unroll
        for (int i = 0; i < 8; ++i)
            #pragma unroll
            for (int j = 0; j < 8; ++j) acc[i][j] = 0.f;

        // prefetch k-tile 0
        float4 vaA = *(const float4*)(z   + (size_t)(rbase + rc0)      * DDIM + kq);
        float4 vaB = *(const float4*)(z   + (size_t)(rbase + rc0 + 64) * DDIM + kq);
        float4 vbA = *(const float4*)(emb + (size_t)(cb + rc0)         * DDIM + kq);
        float4 vbB = *(const float4*)(emb + (size_t)(cb + rc0 + 64)    * DDIM + kq);

        for (int kb = 0; kb < DDIM; kb += KT) {
            // transpose-stage into LDS (2-way banked = free)
            As[kq+0][rc0]    = vaA.x; As[kq+1][rc0]    = vaA.y; As[kq+2][rc0]    = vaA.z; As[kq+3][rc0]    = vaA.w;
            As[kq+0][rc0+64] = vaB.x; As[kq+1][rc0+64] = vaB.y; As[kq+2][rc0+64] = vaB.z; As[kq+3][rc0+64] = vaB.w;
            Bs[kq+0][rc0]    = vbA.x; Bs[kq+1][rc0]    = vbA.y; Bs[kq+2][rc0]    = vbA.z; Bs[kq+3][rc0]    = vbA.w;
            Bs[kq+0][rc0+64] = vbB.x; Bs[kq+1][rc0+64] = vbB.y; Bs[kq+2][rc0+64] = vbB.z; Bs[kq+3][rc0+64] = vbB.w;
            __syncthreads();
            if (kb + KT < DDIM) {   // prefetch next tile; latency hides under FMAs
                const int ko = kb + KT + kq;
                vaA = *(const float4*)(z   + (size_t)(rbase + rc0)      * DDIM + ko);
                vaB = *(const float4*)(z   + (size_t)(rbase + rc0 + 64) * DDIM + ko);
                vbA = *(const float4*)(emb + (size_t)(cb + rc0)         * DDIM + ko);
                vbB = *(const float4*)(emb + (size_t)(cb + rc0 + 64)    * DDIM + ko);
            }
            #pragma unroll
            for (int k = 0; k < KT; ++k) {      // strictly ascending k
                float4 a0 = *(const float4*)&As[k][ty * 8];
                float4 a1 = *(const float4*)&As[k][ty * 8 + 4];
                float4 b0 = *(const float4*)&Bs[k][tx * 4];        // cols 4tx..4tx+3
                float4 b1 = *(const float4*)&Bs[k][64 + tx * 4];   // cols 64+4tx..+3
                float av[8] = {a0.x,a0.y,a0.z,a0.w,a1.x,a1.y,a1.z,a1.w};
                float bv[8] = {b0.x,b0.y,b0.z,b0.w,b1.x,b1.y,b1.z,b1.w};
                #pragma unroll
                for (int i = 0; i < 8; ++i)
                    #pragma unroll
                    for (int j = 0; j < 8; ++j)
                        acc[i][j] = fmaf(av[i], bv[j], acc[i][j]);
            }
            __syncthreads();
        }
        // epilogue: d = fl(fl(zz+ee) - fl(2*dot)); pack (bits(d), col) into u64 min-key
        #pragma unroll
        for (int j = 0; j < 8; ++j) {
            const int col = cb + ((j < 4) ? (tx * 4 + j) : (64 + tx * 4 + (j - 4)));
            const float bn = bnorm[col];
            #pragma unroll
            for (int i = 0; i < 8; ++i) {
                const float s = __fsub_rn(__fadd_rn(zn[i], bn), __fmul_rn(2.f, acc[i][j]));
                const unsigned long long key =
                    ((unsigned long long)__float_as_uint(s) << 32) | (unsigned)col;
                if (key < best[i]) best[i] = key;
            }
        }
    }

    // min-key reduce across the 16 tx lanes (same ty group)
    #pragma unroll
    for (int i = 0; i < 8; ++i) {
        unsigned long long v = best[i];
        #pragma unroll
        for (int m = 1; m < 16; m <<= 1) {
            unsigned long long ov = __shfl_xor(v, m);
            if (ov < v) v = ov;
        }
        if (tx == 0) minkey[(size_t)(rbase + ty * 8 + i) * SPLIT + split] = v;
    }
}

// ---------------- kernel 3: final argmin over splits + gather + STE + partials ----------------
__global__ void k_gather(const float* __restrict__ z, const float* __restrict__ emb,
                         const unsigned long long* __restrict__ minkey,
                         float* __restrict__ out, unsigned* __restrict__ counts,
                         float* __restrict__ d2buf) {
    const int lane = threadIdx.x & 63;
    const int row = blockIdx.x * 4 + (threadIdx.x >> 6);
    unsigned long long v = ~0ULL;
    if (lane < SPLIT) v = minkey[(size_t)row * SPLIT + lane];
    #pragma unroll
    for (int m = 32; m; m >>= 1) {
        unsigned long long ov = __shfl_xor(v, m);
        if (ov < v) v = ov;
    }
    const int id = (int)(v & 0xffffffffu);

    const float* ep = emb + (size_t)id * DDIM;
    const float* zp = z + (size_t)row * DDIM;
    float* op = out + 1 + (size_t)row * DDIM;
    float d2 = 0.f;
    #pragma unroll
    for (int m = 0; m < 8; ++m) {                   // stride-1 coalesced
        const int k = m * 64 + lane;
        const float e = ep[k];
        const float zv = zp[k];
        const float t = e - zv;                     // two-step rounding matches reference STE
        op[k] = zv + t;
        d2 = fmaf(t, t, d2);
    }
    #pragma unroll
    for (int m = 32; m; m >>= 1) d2 += __shfl_xor(d2, m);
    if (lane == 0) {
        atomicAdd(&counts[id], 1u);
        d2buf[row] = d2;
        out[1 + (size_t)NZ + row] = (float)id;
    }
}

// ---------------- kernel 4: finalize loss + perplexity ----------------
__global__ void k_final(const float* __restrict__ d2buf, const unsigned* __restrict__ counts,
                        float* __restrict__ out) {
    __shared__ double sh[256];
    __shared__ float  shf[256];
    const int tid = threadIdx.x;
    double ent = 0.0;
    for (int i = tid; i < NE; i += 256) {
        const double p = (double)counts[i] / (double)NROWS;
        ent += p * log(p + 1e-10);
    }
    float sse = 0.f;
    for (int i = tid; i < NROWS; i += 256) sse += d2buf[i];
    sh[tid] = ent; shf[tid] = sse;
    __syncthreads();
    for (int s = 128; s; s >>= 1) {
        if (tid < s) { sh[tid] += sh[tid + s]; shf[tid] += shf[tid + s]; }
        __syncthreads();
    }
    if (tid == 0) {
        out[0] = 1.25f * (shf[0] / (float)NZ);
        out[1 + (size_t)NZ + NROWS] = (float)exp(-sh[0]);
    }
}

extern "C" void kernel_launch(void* const* d_in, const int* in_sizes, int n_in,
                              void* d_out, int out_size, void* d_ws, size_t ws_size,
                              hipStream_t stream) {
    const float* z   = (const float*)d_in[0];
    const float* emb = (const float*)d_in[1];
    float* out = (float*)d_out;
    char* ws = (char*)d_ws;

    size_t off = 0;
    unsigned long long* minkey = (unsigned long long*)(ws + off);
    off += (size_t)NROWS * SPLIT * 8;                                          // 1MB
    float*    bnorm  = (float*)(ws + off); off += (size_t)NE * 4;              // 16KB
    unsigned* counts = (unsigned*)(ws + off); off += (size_t)NE * 4;           // 16KB
    float*    d2buf  = (float*)(ws + off); off += (size_t)NROWS * 4;           // 64KB
    float*    Bsum   = (float*)(ws + off); off += (size_t)NROWS * 4 * 4;       // 256KB
    float*    znorm  = (float*)(ws + off); off += (size_t)NROWS * 4;           // 64KB

    hipMemsetAsync(counts, 0, NE * sizeof(unsigned), stream);
    k_znormB<<<(NROWS * 4) / 256, 256, 0, stream>>>(z, Bsum);
    k_znfin<<<NROWS / 256, 256, 0, stream>>>(Bsum, znorm);
    k_bnorm<<<64, 256, 0, stream>>>(emb, bnorm);
    k_dist<<<dim3(NROWS / TM, SPLIT), 256, 0, stream>>>(z, emb, bnorm, znorm, minkey);
    k_gather<<<NROWS / 4, 256, 0, stream>>>(z, emb, minkey, out, counts, d2buf);
    k_final<<<1, 256, 0, stream>>>(d2buf, counts, out);
}

// Round 6
// 865.070 us; speedup vs baseline: 1.8718x; 1.3120x over previous
//
#include <hip/hip_runtime.h>
#include <math.h>

#define NROWS 16384      // 32*512
#define DDIM  512
#define NE    4096
#define SPLIT 8
#define CPS   (NE / SPLIT)   // 512 codes per split
#define TM    128
#define TN    128
#define KT    16
#define LDP   132            // padded LDS row stride: staging 2-way, frags broadcast/2-way
#define NZ    (NROWS * DDIM) // 8388608

__device__ __forceinline__ float sqr_rn(float x) { return __fmul_rn(x, x); }

// ---------------- kernel 0a: numpy-exact pairwise partial sums of z*z ----------------
__global__ void k_znormB(const float* __restrict__ z, float* __restrict__ Bsum) {
    const int t = blockIdx.x * blockDim.x + threadIdx.x;   // 0 .. NROWS*4-1
    const int row = t >> 2, blk = t & 3;
    const float4* p = (const float4*)(z + (size_t)row * DDIM + blk * 128);
    float4 v0 = p[0], v1 = p[1];
    float r[8];
    r[0] = sqr_rn(v0.x); r[1] = sqr_rn(v0.y); r[2] = sqr_rn(v0.z); r[3] = sqr_rn(v0.w);
    r[4] = sqr_rn(v1.x); r[5] = sqr_rn(v1.y); r[6] = sqr_rn(v1.z); r[7] = sqr_rn(v1.w);
    #pragma unroll
    for (int i = 1; i < 16; ++i) {
        v0 = p[2 * i]; v1 = p[2 * i + 1];
        r[0] = __fadd_rn(r[0], sqr_rn(v0.x)); r[1] = __fadd_rn(r[1], sqr_rn(v0.y));
        r[2] = __fadd_rn(r[2], sqr_rn(v0.z)); r[3] = __fadd_rn(r[3], sqr_rn(v0.w));
        r[4] = __fadd_rn(r[4], sqr_rn(v1.x)); r[5] = __fadd_rn(r[5], sqr_rn(v1.y));
        r[6] = __fadd_rn(r[6], sqr_rn(v1.z)); r[7] = __fadd_rn(r[7], sqr_rn(v1.w));
    }
    Bsum[t] = __fadd_rn(__fadd_rn(__fadd_rn(r[0], r[1]), __fadd_rn(r[2], r[3])),
                        __fadd_rn(__fadd_rn(r[4], r[5]), __fadd_rn(r[6], r[7])));
}

// ---------------- kernel 0b: combine 4 block sums: (B0+B1)+(B2+B3) ----------------
__global__ void k_znfin(const float* __restrict__ Bsum, float* __restrict__ znorm) {
    const int row = blockIdx.x * blockDim.x + threadIdx.x;
    if (row >= NROWS) return;
    const float4 b = *(const float4*)(Bsum + (size_t)row * 4);
    znorm[row] = __fadd_rn(__fadd_rn(b.x, b.y), __fadd_rn(b.z, b.w));
}

// ---------------- kernel 1: codebook squared norms (sub-ulp of zz; order-free) ----------
__global__ void k_bnorm(const float* __restrict__ emb, float* __restrict__ bnorm) {
    const int lane = threadIdx.x & 63;
    const int wid  = (blockIdx.x * blockDim.x + threadIdx.x) >> 6;
    const int nw   = (gridDim.x * blockDim.x) >> 6;
    for (int c = wid; c < NE; c += nw) {
        const float4* p = (const float4*)(emb + (size_t)c * DDIM);
        float4 v0 = p[lane * 2];
        float4 v1 = p[lane * 2 + 1];
        float s = v0.x*v0.x + v0.y*v0.y + v0.z*v0.z + v0.w*v0.w
                + v1.x*v1.x + v1.y*v1.y + v1.z*v1.z + v1.w*v1.w;
        #pragma unroll
        for (int m = 32; m; m >>= 1) s += __shfl_xor(s, m);
        if (lane == 0) bnorm[c] = s;
    }
}

// ---------------- kernel 2: fused distance GEMM + per-split argmin ----------------
// grid (NROWS/TM, SPLIT), block 256 (tx 0..15, ty 0..15). 8x8 microtile.
// Transient staging (regs live only load->store, as R2's 88-VGPR build; NO cross-compute
// prefetch — R5 showed it balloons VGPR to 180 and halves occupancy).
// d = fl(fl(zz+ee) - fl(2*dot)), dot = sequential ascending-k FMA chain (bit-exact vs np).
__global__ __launch_bounds__(256) void k_dist(const float* __restrict__ z,
                                              const float* __restrict__ emb,
                                              const float* __restrict__ bnorm,
                                              const float* __restrict__ znorm,
                                              unsigned long long* __restrict__ minkey) {
    __shared__ float As[KT][LDP];
    __shared__ float Bs[KT][LDP];
    const int tid = threadIdx.x;
    const int tx = tid & 15, ty = tid >> 4;
    const int rbase = blockIdx.x * TM;
    const int split = blockIdx.y;
    const int rc0 = tid >> 2;               // 0..63
    const int kq  = (tid & 3) * 4;          // 0,4,8,12

    float zn[8];
    #pragma unroll
    for (int i = 0; i < 8; ++i) zn[i] = znorm[rbase + ty * 8 + i];

    unsigned long long best[8];
    #pragma unroll
    for (int i = 0; i < 8; ++i) best[i] = ~0ULL;

    for (int ct = 0; ct < CPS / TN; ++ct) {
        const int cb = split * CPS + ct * TN;
        float acc[8][8];
        #pragma unroll
        for (int i = 0; i < 8; ++i)
            #pragma unroll
            for (int j = 0; j < 8; ++j) acc[i][j] = 0.f;

        for (int kb = 0; kb < DDIM; kb += KT) {
            // stage: issue all 4 loads, then all LDS stores (one vmcnt drain).
            // regs are transient — dead after the stores.
            {
                const float4 vaA = *(const float4*)(z   + (size_t)(rbase + rc0)      * DDIM + kb + kq);
                const float4 vaB = *(const float4*)(z   + (size_t)(rbase + rc0 + 64) * DDIM + kb + kq);
                const float4 vbA = *(const float4*)(emb + (size_t)(cb + rc0)         * DDIM + kb + kq);
                const float4 vbB = *(const float4*)(emb + (size_t)(cb + rc0 + 64)    * DDIM + kb + kq);
                As[kq+0][rc0]    = vaA.x; As[kq+1][rc0]    = vaA.y; As[kq+2][rc0]    = vaA.z; As[kq+3][rc0]    = vaA.w;
                As[kq+0][rc0+64] = vaB.x; As[kq+1][rc0+64] = vaB.y; As[kq+2][rc0+64] = vaB.z; As[kq+3][rc0+64] = vaB.w;
                Bs[kq+0][rc0]    = vbA.x; Bs[kq+1][rc0]    = vbA.y; Bs[kq+2][rc0]    = vbA.z; Bs[kq+3][rc0]    = vbA.w;
                Bs[kq+0][rc0+64] = vbB.x; Bs[kq+1][rc0+64] = vbB.y; Bs[kq+2][rc0+64] = vbB.z; Bs[kq+3][rc0+64] = vbB.w;
            }
            __syncthreads();
            #pragma unroll
            for (int k = 0; k < KT; ++k) {      // strictly ascending k
                float4 a0 = *(const float4*)&As[k][ty * 8];        // broadcast across tx
                float4 a1 = *(const float4*)&As[k][ty * 8 + 4];
                float4 b0 = *(const float4*)&Bs[k][tx * 4];        // cols 4tx..4tx+3 (2-way)
                float4 b1 = *(const float4*)&Bs[k][64 + tx * 4];   // cols 64+4tx..+3
                float av[8] = {a0.x,a0.y,a0.z,a0.w,a1.x,a1.y,a1.z,a1.w};
                float bv[8] = {b0.x,b0.y,b0.z,b0.w,b1.x,b1.y,b1.z,b1.w};
                #pragma unroll
                for (int i = 0; i < 8; ++i)
                    #pragma unroll
                    for (int j = 0; j < 8; ++j)
                        acc[i][j] = fmaf(av[i], bv[j], acc[i][j]);
            }
            __syncthreads();
        }
        // epilogue: d = fl(fl(zz+ee) - fl(2*dot)); pack (bits(d), col) into u64 min-key
        #pragma unroll
        for (int j = 0; j < 8; ++j) {
            const int col = cb + ((j < 4) ? (tx * 4 + j) : (64 + tx * 4 + (j - 4)));
            const float bn = bnorm[col];
            #pragma unroll
            for (int i = 0; i < 8; ++i) {
                const float s = __fsub_rn(__fadd_rn(zn[i], bn), __fmul_rn(2.f, acc[i][j]));
                const unsigned long long key =
                    ((unsigned long long)__float_as_uint(s) << 32) | (unsigned)col;
                if (key < best[i]) best[i] = key;
            }
        }
    }

    // min-key reduce across the 16 tx lanes (same ty group)
    #pragma unroll
    for (int i = 0; i < 8; ++i) {
        unsigned long long v = best[i];
        #pragma unroll
        for (int m = 1; m < 16; m <<= 1) {
            unsigned long long ov = __shfl_xor(v, m);
            if (ov < v) v = ov;
        }
        if (tx == 0) minkey[(size_t)(rbase + ty * 8 + i) * SPLIT + split] = v;
    }
}

// ---------------- kernel 3: final argmin over splits + gather + STE + partials ----------------
__global__ void k_gather(const float* __restrict__ z, const float* __restrict__ emb,
                         const unsigned long long* __restrict__ minkey,
                         float* __restrict__ out, unsigned* __restrict__ counts,
                         float* __restrict__ d2buf) {
    const int lane = threadIdx.x & 63;
    const int row = blockIdx.x * 4 + (threadIdx.x >> 6);
    unsigned long long v = ~0ULL;
    if (lane < SPLIT) v = minkey[(size_t)row * SPLIT + lane];
    #pragma unroll
    for (int m = 32; m; m >>= 1) {
        unsigned long long ov = __shfl_xor(v, m);
        if (ov < v) v = ov;
    }
    const int id = (int)(v & 0xffffffffu);

    const float* ep = emb + (size_t)id * DDIM;
    const float* zp = z + (size_t)row * DDIM;
    float* op = out + 1 + (size_t)row * DDIM;
    float d2 = 0.f;
    #pragma unroll
    for (int m = 0; m < 8; ++m) {                   // stride-1 coalesced
        const int k = m * 64 + lane;
        const float e = ep[k];
        const float zv = zp[k];
        const float t = e - zv;                     // two-step rounding matches reference STE
        op[k] = zv + t;
        d2 = fmaf(t, t, d2);
    }
    #pragma unroll
    for (int m = 32; m; m >>= 1) d2 += __shfl_xor(d2, m);
    if (lane == 0) {
        atomicAdd(&counts[id], 1u);
        d2buf[row] = d2;
        out[1 + (size_t)NZ + row] = (float)id;
    }
}

// ---------------- kernel 4: finalize loss + perplexity ----------------
__global__ void k_final(const float* __restrict__ d2buf, const unsigned* __restrict__ counts,
                        float* __restrict__ out) {
    __shared__ double sh[256];
    __shared__ float  shf[256];
    const int tid = threadIdx.x;
    double ent = 0.0;
    for (int i = tid; i < NE; i += 256) {
        const double p = (double)counts[i] / (double)NROWS;
        ent += p * log(p + 1e-10);
    }
    float sse = 0.f;
    for (int i = tid; i < NROWS; i += 256) sse += d2buf[i];
    sh[tid] = ent; shf[tid] = sse;
    __syncthreads();
    for (int s = 128; s; s >>= 1) {
        if (tid < s) { sh[tid] += sh[tid + s]; shf[tid] += shf[tid + s]; }
        __syncthreads();
    }
    if (tid == 0) {
        out[0] = 1.25f * (shf[0] / (float)NZ);
        out[1 + (size_t)NZ + NROWS] = (float)exp(-sh[0]);
    }
}

extern "C" void kernel_launch(void* const* d_in, const int* in_sizes, int n_in,
                              void* d_out, int out_size, void* d_ws, size_t ws_size,
                              hipStream_t stream) {
    const float* z   = (const float*)d_in[0];
    const float* emb = (const float*)d_in[1];
    float* out = (float*)d_out;
    char* ws = (char*)d_ws;

    size_t off = 0;
    unsigned long long* minkey = (unsigned long long*)(ws + off);
    off += (size_t)NROWS * SPLIT * 8;                                          // 1MB
    float*    bnorm  = (float*)(ws + off); off += (size_t)NE * 4;              // 16KB
    unsigned* counts = (unsigned*)(ws + off); off += (size_t)NE * 4;           // 16KB
    float*    d2buf  = (float*)(ws + off); off += (size_t)NROWS * 4;           // 64KB
    float*    Bsum   = (float*)(ws + off); off += (size_t)NROWS * 4 * 4;       // 256KB
    float*    znorm  = (float*)(ws + off); off += (size_t)NROWS * 4;           // 64KB

    hipMemsetAsync(counts, 0, NE * sizeof(unsigned), stream);
    k_znormB<<<(NROWS * 4) / 256, 256, 0, stream>>>(z, Bsum);
    k_znfin<<<NROWS / 256, 256, 0, stream>>>(Bsum, znorm);
    k_bnorm<<<64, 256, 0, stream>>>(emb, bnorm);
    k_dist<<<dim3(NROWS / TM, SPLIT), 256, 0, stream>>>(z, emb, bnorm, znorm, minkey);
    k_gather<<<NROWS / 4, 256, 0, stream>>>(z, emb, minkey, out, counts, d2buf);
    k_final<<<1, 256, 0, stream>>>(d2buf, counts, out);
}